// Round 5
// baseline (511.135 us; speedup 1.0000x reference)
//
#include <hip/hip_runtime.h>
#include <math.h>

typedef _Float16 f16_t;
typedef _Float16 f16x8 __attribute__((ext_vector_type(8)));
typedef _Float16 f16x4 __attribute__((ext_vector_type(4)));
typedef float    f32x4 __attribute__((ext_vector_type(4)));

#define NHC 128          // NH
#define NBATCH 16
#define JT 128           // output cols per block
#define THREADS 512
#define L0LEN 16384
#define LDSROWPITCH 272  // 128*2 bytes + 16 pad
#define TREGION (130*LDSROWPITCH)   // 260 staged rows max (130 per parity region)

__device__ __host__ __forceinline__ int nstep_f(int n){ int m = n - 4; m = m < 0 ? 0 : m; return ((m + 1) >> 1) + 1; }

// ---------------- prep: W[c][i][k] fp32 -> Wt[k][c][i] fp16; depth-channel prefix sums; fp32 bias ----------------
__global__ void prep_kernel(const float* __restrict__ W, const float* __restrict__ bin,
                            f16_t* __restrict__ Wt, float* __restrict__ Pp, float* __restrict__ biasf)
{
    int c = blockIdx.x;      // 0..383
    int i = threadIdx.x;     // 0..127
    #pragma unroll
    for (int k = 0; k < 4; k++)
        Wt[((size_t)k*384 + c)*128 + i] = (f16_t)W[((size_t)c*129 + i)*4 + k];
    if (i == 0) {
        float s = 0.f;
        Pp[c*5 + 0] = 0.f;
        #pragma unroll
        for (int k = 0; k < 4; k++) { s += W[((size_t)c*129 + 128)*4 + k]; Pp[c*5 + k + 1] = s; }
        biasf[c] = bin[c];
    }
}

// ---------------- GEMM: software-pipelined taps (ping-pong A buffers), LDS B, CTM live col-tiles ----------------
// Per tap: 12 f16x8 A-loads issued while previous tap's MFMAs run -> latency hidden, no vmcnt(0) drain.
// Live regs: Xa+Xb = 96, acc <= 96 -> fits the 256-VGPR cap from __launch_bounds__(512,2).
template<int CTM>
__device__ __forceinline__ void gemm_pipe(f32x4 (&acc)[3][8], const f16_t* __restrict__ Wt,
                                          const char* ldsIn, int arow, int n16, int q, int jt)
{
    f16x8 Xa[3][4], Xb[3][4];   // [segment l/r/g][kc]
    auto loadtap = [&](f16x8 (&X)[3][4], int k){
        const f16_t* ab = Wt + ((size_t)k*384 + arow)*128 + q*8;
        #pragma unroll
        for (int kc = 0; kc < 4; kc++) {
            X[0][kc] = *(const f16x8*)(ab + kc*32);
            X[1][kc] = *(const f16x8*)(ab + 16384 + kc*32);   // +128 rows
            X[2][kc] = *(const f16x8*)(ab + 32768 + kc*32);   // +256 rows
        }
    };
    auto mfmatap = [&](const f16x8 (&X)[3][4], int k){
        const char* bb0 = ldsIn + (k&1)*TREGION + ((k>>1) + n16 + jt*16)*LDSROWPITCH + q*16;
        #pragma unroll
        for (int kc = 0; kc < 4; kc++)
            #pragma unroll
            for (int ct = 0; ct < CTM; ct++) {
                f16x8 bb = *(const f16x8*)(bb0 + ct*(16*LDSROWPITCH) + kc*64);
                acc[0][ct] = __builtin_amdgcn_mfma_f32_16x16x32_f16(X[0][kc], bb, acc[0][ct], 0, 0, 0);
                acc[1][ct] = __builtin_amdgcn_mfma_f32_16x16x32_f16(X[1][kc], bb, acc[1][ct], 0, 0, 0);
                acc[2][ct] = __builtin_amdgcn_mfma_f32_16x16x32_f16(X[2][kc], bb, acc[2][ct], 0, 0, 0);
            }
    };
    loadtap(Xa, 0);
    loadtap(Xb, 1);  mfmatap(Xa, 0);
    loadtap(Xa, 2);  mfmatap(Xb, 1);
    loadtap(Xb, 3);  mfmatap(Xa, 2);
                     mfmatap(Xb, 3);
}

__device__ __forceinline__ void load_biasp(float (&biasr)[3][4], float (&pfull)[3][4],
                                           const float* __restrict__ biasf,
                                           const float* __restrict__ Pp, int cw)
{
    #pragma unroll
    for (int s = 0; s < 3; s++)
        #pragma unroll
        for (int r = 0; r < 4; r++) {
            int row = s*128 + cw + r;
            biasr[s][r] = biasf[row];
            pfull[s][r] = Pp[row*5 + 4];
        }
}

// ---------------- gated epilogue; CTE column-tiles (skipped tiles must be all-masked) ----------------
template<int CTE, bool TO_LDS>
__device__ __forceinline__ void epilogue_store(
    const f32x4 (&acc)[3][8], char* ldsOut, f16_t* goutB,
    const float (&biasr)[3][4], const float (&pfull)[3][4],
    const float* __restrict__ Pp, float* __restrict__ outrow,
    int j0, int Nt, int Nt1, float dval, bool record, int n16, int cw)
{
    #pragma unroll
    for (int ct = 0; ct < CTE; ct++) {
        int j = j0 + ct*16 + n16;
        int cnt = Nt - 2*j; cnt = cnt < 0 ? 0 : (cnt > 4 ? 4 : cnt);
        bool zero = (j >= Nt1);
        float hv[4];
        #pragma unroll
        for (int r = 0; r < 4; r++) {
            float d0, d1, d2;
            if (cnt == 4)      { d0 = pfull[0][r]; d1 = pfull[1][r]; d2 = pfull[2][r]; }
            else if (cnt == 0) { d0 = 0.f; d1 = 0.f; d2 = 0.f; }
            else { int rw = cw + r; d0 = Pp[rw*5 + cnt]; d1 = Pp[(128+rw)*5 + cnt]; d2 = Pp[(256+rw)*5 + cnt]; }
            float lv = acc[0][ct][r] + biasr[0][r] + dval*d0;
            float rp = acc[1][ct][r] + biasr[1][r] + dval*d1;
            float gp = acc[2][ct][r] + biasr[2][r] + dval*d2;
            float e2 = __expf(2.f*rp);
            float rv = 1.f - 2.f/(e2 + 1.f);          // tanh
            float gv = 1.f/(1.f + __expf(-gp));       // sigmoid
            float hh = lv*gv + rv*(1.f - gv);
            hv[r] = zero ? 0.f : hh;
        }
        f16x4 hb;
        #pragma unroll
        for (int r = 0; r < 4; r++) hb[r] = (f16_t)hv[r];
        if constexpr (TO_LDS) {
            *(f16x4*)(ldsOut + (j&1)*TREGION + (j>>1)*LDSROWPITCH + cw*2) = hb;
        } else {
            *(f16x4*)(goutB + (ct*16 + n16)*NHC + cw) = hb;
        }
        if (record && ct == 0 && n16 == 0) {
            #pragma unroll
            for (int r = 0; r < 4; r++) outrow[cw + r] = hv[r];
        }
    }
}

// ---------------- one conv depth: X_t -> X_{t+1}; t==0 reads h directly (fused transpose) ----------------
__global__ __launch_bounds__(THREADS, 2) void conv_kernel(
    const float* __restrict__ h, const f16_t* __restrict__ Xin, f16_t* __restrict__ Xout,
    const f16_t* __restrict__ Wt, const float* __restrict__ Pp,
    const float* __restrict__ biasf, const int* __restrict__ N0,
    float* __restrict__ outbuf,
    int t, int inCols, int outCols, float dval)
{
    __shared__ alignas(16) char ldsX[2*TREGION];
    const int b  = blockIdx.y;
    const int j0 = blockIdx.x * JT;
    const int tid = threadIdx.x;
    int Nt = N0[b];
    for (int s = 0; s < t; s++) Nt = nstep_f(Nt);
    const int Nt1 = nstep_f(Nt);

    f16_t* XoutB = Xout + ((size_t)b*outCols + j0)*NHC;
    if (j0 >= Nt1) {                         // fully-masked tile: just zero it
        float4 z = {0.f,0.f,0.f,0.f};
        float4* p = (float4*)XoutB;
        #pragma unroll
        for (int i = 0; i < 4; i++) p[i*THREADS + tid] = z;
        return;
    }

    if (t == 0) {
        // fused transpose staging: h (b, ch, pos fp32) -> parity-split pos-major f16 LDS, mask p>=N.
        // 8 channels buffered in regs -> two f16x8 LDS writes per group (not 16 scalar writes).
        const float* hB = h + (size_t)b*NHC*L0LEN;
        const int P0 = 2*j0;
        const int s4 = tid >> 7;             // 0..3 channel slot
        const int pr = tid & 127;            // position-pair 0..127 (wave-contiguous -> coalesced)
        const int p  = P0 + pr*2;
        const bool full = (p + 1 < Nt), half = (p < Nt);
        #pragma unroll 1
        for (int g = 0; g < 4; g++) {
            int cbase = s4*32 + g*8;
            f16x8 ev, od;
            #pragma unroll
            for (int e = 0; e < 8; e++) {
                float2 v = {0.f, 0.f};
                if (full)      v = *(const float2*)(hB + (size_t)(cbase + e)*L0LEN + p);
                else if (half) v.x = hB[(size_t)(cbase + e)*L0LEN + p];
                ev[e] = (f16_t)v.x; od[e] = (f16_t)v.y;
            }
            char* wb = ldsX + pr*LDSROWPITCH + cbase*2;
            *(f16x8*)(wb)           = ev;    // even row 2*pr
            *(f16x8*)(wb + TREGION) = od;    // odd  row 2*pr+1
        }
        if (tid < 128) {                     // pair 128 -> rows 256,257
            int c = tid, pe = P0 + 256;
            float2 v = {0.f, 0.f};
            if (pe + 1 < Nt)  v = *(const float2*)(hB + (size_t)c*L0LEN + pe);
            else if (pe < Nt) v.x = hB[(size_t)c*L0LEN + pe];
            char* wb = ldsX + 128*LDSROWPITCH + c*2;
            *(f16_t*)(wb)           = (f16_t)v.x;
            *(f16_t*)(wb + TREGION) = (f16_t)v.y;
        }
    } else {
        // stage up to 258 input rows (pos-major, 256B each) into parity-split padded LDS
        const char* XinB = (const char*)(Xin + ((size_t)b*inCols + 2*(size_t)j0)*NHC);
        const int maxrow = inCols - 2*j0;    // rows available in this batch's buffer
        for (int it = 0; it < 9; ++it) {
            int idx = it*THREADS + tid;
            if (idx < 258*16) {
                int row = idx >> 4, cb = (idx & 15) * 16;
                float4 v = {0.f,0.f,0.f,0.f};
                if (row < maxrow) v = *(const float4*)(XinB + row*256 + cb);
                *(float4*)(ldsX + (row&1)*TREGION + (row>>1)*LDSROWPITCH + cb) = v;
            }
        }
    }
    __syncthreads();

    const int w    = tid >> 6;
    const int lane = tid & 63;
    const int n16  = lane & 15;
    const int q    = lane >> 4;
    const int arow = w*16 + n16;
    const int cw   = w*16 + q*4;

    f32x4 acc[3][8] = {};
    int ctm = (Nt1 - j0 + 15) >> 4; if (ctm > 8) ctm = 8;   // live column-tiles in this block
    switch (ctm) {
    case 1:  gemm_pipe<1>(acc, Wt, ldsX, arow, n16, q, 0); break;
    case 2:  gemm_pipe<2>(acc, Wt, ldsX, arow, n16, q, 0); break;
    case 3:  gemm_pipe<3>(acc, Wt, ldsX, arow, n16, q, 0); break;
    case 4:  gemm_pipe<4>(acc, Wt, ldsX, arow, n16, q, 0); break;
    case 5:  gemm_pipe<5>(acc, Wt, ldsX, arow, n16, q, 0); break;
    case 6:  gemm_pipe<6>(acc, Wt, ldsX, arow, n16, q, 0); break;
    case 7:  gemm_pipe<7>(acc, Wt, ldsX, arow, n16, q, 0); break;
    default: gemm_pipe<8>(acc, Wt, ldsX, arow, n16, q, 0); break;
    }
    // tiles ct >= ctm have j >= Nt1 for every lane -> epilogue's zero flag emits zeros (acc unused)

    // epilogue constants loaded after the GEMM so they don't hold registers during it
    float biasr[3][4], pfull[3][4];
    load_biasp(biasr, pfull, biasf, Pp, cw);

    bool newly = (Nt1 == 1) && (t == 0 || Nt > 1);
    epilogue_store<8, false>(acc, nullptr, XoutB, biasr, pfull, Pp, outbuf + b*NHC,
                             j0, Nt, Nt1, dval, newly && (j0 == 0), n16, cw);
}

// ---------------- tail: one depth pass, CTM live column-tiles starting at tile jt ----------------
// In-place LDS safety (verified R4): pass A (jt=0) writes rows <= 31 after its barrier; pass B (jt=4)
// reads rows 64..128 (disjoint), writes rows 32..63. Stale higher rows feed only masked cols later.
template<int CTM>
__device__ __forceinline__ void tail_iter(
    char* ldsX, const f16_t* __restrict__ Wt,
    const float (&biasr)[3][4], const float (&pfull)[3][4],
    const float* __restrict__ Pp, float* __restrict__ outrow,
    int n16, int q, int arow, int cw, int jt, int Nt, int Nt1, float dval, bool newly)
{
    f32x4 acc[3][8] = {};
    gemm_pipe<CTM>(acc, Wt, ldsX, arow, n16, q, jt);
    __syncthreads();   // all LDS reads complete before in-place writes
    epilogue_store<CTM, true>(acc, ldsX, nullptr, biasr, pfull, Pp, outrow,
                              jt*16, Nt, Nt1, dval, newly, n16, cw);
}

// ---------------- tail: depths 6..12 entirely in LDS, one block per batch ----------------
__global__ __launch_bounds__(THREADS, 2) void tail_kernel(
    const f16_t* __restrict__ Xin, const f16_t* __restrict__ Wt,
    const float* __restrict__ Pp, const float* __restrict__ biasf,
    const int* __restrict__ N0, float* __restrict__ outbuf, int inCols)
{
    __shared__ alignas(16) char ldsX[2*TREGION];
    const int b = blockIdx.x;
    const int tid = threadIdx.x;
    int Nt = N0[b];
    for (int s = 0; s < 6; s++) Nt = nstep_f(Nt);
    if (Nt <= 1) return;                     // finished during conv phase; already recorded

    const int w    = tid >> 6;
    const int lane = tid & 63;
    const int n16  = lane & 15;
    const int q    = lane >> 4;
    const int arow = w*16 + n16;
    const int cw   = w*16 + q*4;
    float* outrow  = outbuf + b*NHC;

    // stage up to 256 input rows (X6, pos-major) into parity-split padded LDS
    const char* XinB = (const char*)(Xin + (size_t)b*inCols*NHC);
    for (int it = 0; it < 8; ++it) {
        int idx = it*THREADS + tid;          // 256 rows x 16 chunks = 4096 = 8*512
        int row = idx >> 4, cb = (idx & 15) * 16;
        float4 v = {0.f,0.f,0.f,0.f};
        if (row < inCols) v = *(const float4*)(XinB + row*256 + cb);
        *(float4*)(ldsX + (row&1)*TREGION + (row>>1)*LDSROWPITCH + cb) = v;
    }

    // depth-invariant epilogue parameters, hoisted out of the depth loop
    float biasr[3][4], pfull[3][4];
    load_biasp(biasr, pfull, biasf, Pp, cw);
    __syncthreads();

    for (int t = 6; t < 13; ++t) {
        int Nt1 = nstep_f(Nt);
        bool newly = (Nt1 == 1);             // Nt > 1 guaranteed inside the loop
        float dval = log1pf((float)t);
        int ctmax = (Nt1 >> 4) + 1; if (ctmax > 8) ctmax = 8;
        int cA = ctmax > 4 ? 4 : ctmax;
        switch (cA) {
        case 1:  tail_iter<1>(ldsX, Wt, biasr, pfull, Pp, outrow, n16, q, arow, cw, 0, Nt, Nt1, dval, newly); break;
        case 2:  tail_iter<2>(ldsX, Wt, biasr, pfull, Pp, outrow, n16, q, arow, cw, 0, Nt, Nt1, dval, newly); break;
        case 3:  tail_iter<3>(ldsX, Wt, biasr, pfull, Pp, outrow, n16, q, arow, cw, 0, Nt, Nt1, dval, newly); break;
        default: tail_iter<4>(ldsX, Wt, biasr, pfull, Pp, outrow, n16, q, arow, cw, 0, Nt, Nt1, dval, newly); break;
        }
        if (ctmax > 4) {                     // t==6 only (Nt1 up to 127)
            switch (ctmax - 4) {
            case 1:  tail_iter<1>(ldsX, Wt, biasr, pfull, Pp, outrow, n16, q, arow, cw, 4, Nt, Nt1, dval, false); break;
            case 2:  tail_iter<2>(ldsX, Wt, biasr, pfull, Pp, outrow, n16, q, arow, cw, 4, Nt, Nt1, dval, false); break;
            case 3:  tail_iter<3>(ldsX, Wt, biasr, pfull, Pp, outrow, n16, q, arow, cw, 4, Nt, Nt1, dval, false); break;
            default: tail_iter<4>(ldsX, Wt, biasr, pfull, Pp, outrow, n16, q, arow, cw, 4, Nt, Nt1, dval, false); break;
            }
        }
        if (newly) return;                   // result recorded; this batch is done
        Nt = Nt1;
        __syncthreads();                     // writes visible before next depth's reads
    }
}

// ---------------- finalize: stable rank by finish depth, emit fp32 ----------------
__global__ void finalize_kernel(const float* __restrict__ outbuf,
                                const int* __restrict__ N0, float* __restrict__ dout)
{
    __shared__ int fin[16];
    __shared__ int rnk[16];
    int tid = threadIdx.x;
    if (tid < 16) {
        int n = N0[tid]; int f = 12;
        for (int t = 0; t < 13; t++) { n = nstep_f(n); if (n == 1) { f = t; break; } }
        fin[tid] = f;
    }
    __syncthreads();
    if (tid < 16) {
        int r = 0;
        for (int b2 = 0; b2 < 16; b2++)
            if (fin[b2] < fin[tid] || (fin[b2] == fin[tid] && b2 < tid)) r++;
        rnk[tid] = r;
    }
    __syncthreads();
    for (int e = tid; e < NBATCH*NHC; e += 256) {
        int b = e >> 7, c = e & 127;
        dout[rnk[b]*NHC + c] = outbuf[e];
    }
}

extern "C" void kernel_launch(void* const* d_in, const int* in_sizes, int n_in,
                              void* d_out, int out_size, void* d_ws, size_t ws_size,
                              hipStream_t stream)
{
    const float* h    = (const float*)d_in[0];
    const int*   N0   = (const int*)d_in[1];
    const float* W    = (const float*)d_in[2];
    const float* bvec = (const float*)d_in[3];
    float* dout = (float*)d_out;

    int Ls[14], Ms[14];
    Ls[0] = L0LEN;
    for (int t = 0; t < 13; t++) Ls[t+1] = nstep_f(Ls[t]);
    for (int t = 0; t < 14; t++) Ms[t] = ((Ls[t] + 127) / 128) * 128;   // JT=128-aligned

    char* ws = (char*)d_ws;
    size_t off = 0;
    auto alloc = [&](size_t bytes){ size_t o = off; off += (bytes + 255) & ~(size_t)255; return o; };
    size_t oXA   = alloc((size_t)NBATCH * Ms[1] * NHC * 2);   // X1, X3, X5
    size_t oXB   = alloc((size_t)NBATCH * Ms[2] * NHC * 2);   // X2, X4, X6
    size_t oWt   = alloc((size_t)4*384*128*2);
    size_t oPp   = alloc((size_t)384*5*4);
    size_t oBias = alloc((size_t)384*4);
    size_t oOut  = alloc((size_t)NBATCH*NHC*4);
    f16_t* XA    = (f16_t*)(ws + oXA);
    f16_t* XB    = (f16_t*)(ws + oXB);
    f16_t* Wt    = (f16_t*)(ws + oWt);
    float* Pp    = (float*)(ws + oPp);
    float* biasf = (float*)(ws + oBias);
    float* outb  = (float*)(ws + oOut);

    hipLaunchKernelGGL(prep_kernel, dim3(384), dim3(128), 0, stream, W, bvec, Wt, Pp, biasf);

    // t=0 reads h directly (fused transpose); afterwards ping-pong XA/XB
    f16_t* cur = XA; f16_t* nxt = XB;
    hipLaunchKernelGGL(conv_kernel, dim3(Ms[1]/JT, NBATCH), dim3(THREADS), 0, stream,
                       h, (const f16_t*)nullptr, XA, Wt, Pp, biasf, N0, outb,
                       0, Ms[0], Ms[1], log1pf(0.f));
    for (int t = 1; t < 6; t++) {
        hipLaunchKernelGGL(conv_kernel, dim3(Ms[t+1]/JT, NBATCH), dim3(THREADS), 0, stream,
                           h, cur, nxt, Wt, Pp, biasf, N0, outb, t, Ms[t], Ms[t+1], log1pf((float)t));
        f16_t* tmp = cur; cur = nxt; nxt = tmp;
    }
    // cur == X6 (t=1,3,5 wrote XB,XA,XB -> cur==XB)
    hipLaunchKernelGGL(tail_kernel, dim3(NBATCH), dim3(THREADS), 0, stream,
                       cur, Wt, Pp, biasf, N0, outb, Ms[6]);
    hipLaunchKernelGGL(finalize_kernel, dim3(1), dim3(256), 0, stream, outb, N0, dout);
}

// Round 6
// 438.135 us; speedup vs baseline: 1.1666x; 1.1666x over previous
//
#include <hip/hip_runtime.h>
#include <math.h>

typedef _Float16 f16_t;
typedef _Float16 f16x8 __attribute__((ext_vector_type(8)));
typedef _Float16 f16x4 __attribute__((ext_vector_type(4)));
typedef float    f32x4 __attribute__((ext_vector_type(4)));

#define NHC 128          // NH
#define NBATCH 16
#define JT 64            // output cols per conv block
#define THREADS 512
#define TTHREADS 256
#define L0LEN 16384
#define LDSROWPITCH 272  // 128*2 bytes + 16 pad -> 2-way-max bank aliasing on b128 reads
#define LDSREGION (66*LDSROWPITCH)   // conv: 130 staged rows (65 per parity region + margin)
#define TREG (130*LDSROWPITCH)       // tail: 258 staged rows (129 per parity region + margin)

__device__ __host__ __forceinline__ int nstep_f(int n){ int m = n - 4; m = m < 0 ? 0 : m; return ((m + 1) >> 1) + 1; }

// ---------------- prep: W[c][i][k] fp32 -> Wt[k][c][i] fp16; depth-channel prefix sums; fp32 bias ----------------
__global__ void prep_kernel(const float* __restrict__ W, const float* __restrict__ bin,
                            f16_t* __restrict__ Wt, float* __restrict__ Pp, float* __restrict__ biasf)
{
    int c = blockIdx.x;      // 0..383
    int i = threadIdx.x;     // 0..127
    #pragma unroll
    for (int k = 0; k < 4; k++)
        Wt[((size_t)k*384 + c)*128 + i] = (f16_t)W[((size_t)c*129 + i)*4 + k];
    if (i == 0) {
        float s = 0.f;
        Pp[c*5 + 0] = 0.f;
        #pragma unroll
        for (int k = 0; k < 4; k++) { s += W[((size_t)c*129 + 128)*4 + k]; Pp[c*5 + k + 1] = s; }
        biasf[c] = bin[c];
    }
}

// ---------------- GEMM: per-tap batched A loads (12 in flight, 48 VGPR), LDS B, CTM live col-tiles ----------------
// #pragma unroll 1 on k keeps only one tap's A-fragments live -> no spill; one vmcnt wait per tap.
template<int CTM>
__device__ __forceinline__ void gemm_tap(f32x4 (&acc)[3][4], const f16_t* __restrict__ Wt,
                                         const char* ldsIn, int arow, int n16, int q)
{
    #pragma unroll 1
    for (int k = 0; k < 4; k++) {
        const f16_t* ab = Wt + ((size_t)k*384 + arow)*128 + q*8;
        f16x8 a0[4], a1[4], a2[4];
        #pragma unroll
        for (int kc = 0; kc < 4; kc++) {
            a0[kc] = *(const f16x8*)(ab + kc*32);
            a1[kc] = *(const f16x8*)(ab + 16384 + kc*32);   // +128 rows
            a2[kc] = *(const f16x8*)(ab + 32768 + kc*32);   // +256 rows
        }
        const char* bb0 = ldsIn + (k&1)*LDSREGION + ((k>>1) + n16)*LDSROWPITCH + q*16;
        #pragma unroll
        for (int kc = 0; kc < 4; kc++) {
            #pragma unroll
            for (int ct = 0; ct < CTM; ct++) {
                f16x8 bb = *(const f16x8*)(bb0 + ct*(16*LDSROWPITCH) + kc*64);
                acc[0][ct] = __builtin_amdgcn_mfma_f32_16x16x32_f16(a0[kc], bb, acc[0][ct], 0, 0, 0);
                acc[1][ct] = __builtin_amdgcn_mfma_f32_16x16x32_f16(a1[kc], bb, acc[1][ct], 0, 0, 0);
                acc[2][ct] = __builtin_amdgcn_mfma_f32_16x16x32_f16(a2[kc], bb, acc[2][ct], 0, 0, 0);
            }
        }
    }
}

__device__ __forceinline__ void load_biasp(float (&biasr)[3][4], float (&pfull)[3][4],
                                           const float* __restrict__ biasf,
                                           const float* __restrict__ Pp, int cw)
{
    #pragma unroll
    for (int s = 0; s < 3; s++)
        #pragma unroll
        for (int r = 0; r < 4; r++) {
            int row = s*128 + cw + r;
            biasr[s][r] = biasf[row];
            pfull[s][r] = Pp[row*5 + 4];
        }
}

// ---------------- one conv depth: X_t -> X_{t+1}; t==0 reads h directly (fused transpose) ----------------
__global__ __launch_bounds__(THREADS) void conv_kernel(
    const float* __restrict__ h, const f16_t* __restrict__ Xin, f16_t* __restrict__ Xout,
    const f16_t* __restrict__ Wt, const float* __restrict__ Pp,
    const float* __restrict__ biasf, const int* __restrict__ N0,
    float* __restrict__ outbuf,
    int t, int inCols, int outCols, float dval)
{
    __shared__ alignas(16) char ldsX[2*LDSREGION];
    const int b  = blockIdx.y;
    const int j0 = blockIdx.x * JT;
    const int tid = threadIdx.x;
    int Nt = N0[b];
    for (int s = 0; s < t; s++) Nt = nstep_f(Nt);
    const int Nt1 = nstep_f(Nt);

    f16_t* XoutB = Xout + ((size_t)b*outCols + j0)*NHC;
    if (j0 >= Nt1) {
        // Only cols Nt1, Nt1+1 of this level are ever read downstream (max live read = col Nt).
        // First dead tile zeroes those 2 rows; deeper dead tiles return immediately.
        if (j0 <= Nt1 + 1 && tid < 32) {
            float4 z = {0.f,0.f,0.f,0.f};
            ((float4*)XoutB)[tid] = z;   // 32 x 16B = 512 B = cols j0, j0+1
        }
        return;
    }

    if (t == 0) {
        // fused transpose staging: h (b, ch, pos fp32) -> parity-split pos-major f16 LDS, mask p>=N
        const float* hB = h + (size_t)b*NHC*L0LEN;
        const int P0 = 2*j0;
        const int jpr = tid & 63;            // position-pair index (wave-contiguous -> coalesced)
        const int s8  = tid >> 6;            // channel slot
        #pragma unroll
        for (int cg = 0; cg < 16; cg++) {
            int c = cg*8 + s8;
            int p = P0 + jpr*2;
            float2 v = {0.f, 0.f};
            if (p + 1 < Nt)      v = *(const float2*)(hB + (size_t)c*L0LEN + p);
            else if (p < Nt)     v.x = hB[(size_t)c*L0LEN + p];
            char* wb = ldsX + jpr*LDSROWPITCH + c*2;
            *(f16_t*)(wb)             = (f16_t)v.x;   // even row 2*jpr
            *(f16_t*)(wb + LDSREGION) = (f16_t)v.y;   // odd  row 2*jpr+1
        }
        if (tid < 128) {                     // halo rows 128,129
            int c = tid;
            int p = P0 + 128;
            float2 v = {0.f, 0.f};
            if (p + 1 < Nt)      v = *(const float2*)(hB + (size_t)c*L0LEN + p);
            else if (p < Nt)     v.x = hB[(size_t)c*L0LEN + p];
            char* wb = ldsX + 64*LDSROWPITCH + c*2;
            *(f16_t*)(wb)             = (f16_t)v.x;
            *(f16_t*)(wb + LDSREGION) = (f16_t)v.y;
        }
    } else {
        // stage up to 130 input rows (pos-major, 256B each) into parity-split padded LDS
        const char* XinB = (const char*)(Xin + ((size_t)b*inCols + 2*(size_t)j0)*NHC);
        const int maxrow = inCols - 2*j0;    // rows available in this batch's buffer
        for (int it = 0; it < 5; ++it) {
            int idx = it*THREADS + tid;
            if (idx < 130*16) {
                int row = idx >> 4, cb = (idx & 15) * 16;
                float4 v = {0.f,0.f,0.f,0.f};
                if (row < maxrow) v = *(const float4*)(XinB + row*256 + cb);
                *(float4*)(ldsX + (row&1)*LDSREGION + (row>>1)*LDSROWPITCH + cb) = v;
            }
        }
    }
    __syncthreads();

    const int w    = tid >> 6;
    const int lane = tid & 63;
    const int n16  = lane & 15;
    const int q    = lane >> 4;
    const int arow = w*16 + n16;
    const int cw   = w*16 + q*4;

    f32x4 acc[3][4] = {};
    int ctm = (Nt1 - j0 + 15) >> 4; if (ctm > 4) ctm = 4;   // live column-tiles in this block
    switch (ctm) {
    case 1:  gemm_tap<1>(acc, Wt, ldsX, arow, n16, q); break;
    case 2:  gemm_tap<2>(acc, Wt, ldsX, arow, n16, q); break;
    case 3:  gemm_tap<3>(acc, Wt, ldsX, arow, n16, q); break;
    default: gemm_tap<4>(acc, Wt, ldsX, arow, n16, q); break;
    }
    // tiles ct >= ctm have j >= Nt1 for every lane -> epilogue's zero flag emits zeros (acc unused)

    // epilogue constants loaded after the GEMM so they don't hold registers during it
    float biasr[3][4], pfull[3][4];
    load_biasp(biasr, pfull, biasf, Pp, cw);

    bool newly = (Nt1 == 1) && (t == 0 || Nt > 1);
    bool record = newly && (j0 == 0);
    float* outrow = outbuf + b*NHC;

    #pragma unroll
    for (int ct = 0; ct < 4; ct++) {
        int j = j0 + ct*16 + n16;
        int cnt = Nt - 2*j; cnt = cnt < 0 ? 0 : (cnt > 4 ? 4 : cnt);
        bool zero = (j >= Nt1);
        float hv[4];
        #pragma unroll
        for (int r = 0; r < 4; r++) {
            float d0, d1, d2;
            if (cnt == 4)      { d0 = pfull[0][r]; d1 = pfull[1][r]; d2 = pfull[2][r]; }
            else if (cnt == 0) { d0 = 0.f; d1 = 0.f; d2 = 0.f; }
            else { int rw = cw + r; d0 = Pp[rw*5 + cnt]; d1 = Pp[(128+rw)*5 + cnt]; d2 = Pp[(256+rw)*5 + cnt]; }
            float lv = acc[0][ct][r] + biasr[0][r] + dval*d0;
            float rp = acc[1][ct][r] + biasr[1][r] + dval*d1;
            float gp = acc[2][ct][r] + biasr[2][r] + dval*d2;
            float e2 = __expf(2.f*rp);
            float rv = 1.f - 2.f/(e2 + 1.f);          // tanh
            float gv = 1.f/(1.f + __expf(-gp));       // sigmoid
            float hh = lv*gv + rv*(1.f - gv);
            hv[r] = zero ? 0.f : hh;
        }
        f16x4 hb;
        #pragma unroll
        for (int r = 0; r < 4; r++) hb[r] = (f16_t)hv[r];
        *(f16x4*)(XoutB + (ct*16 + n16)*NHC + cw) = hb;
        if (record && ct == 0 && n16 == 0) {
            #pragma unroll
            for (int r = 0; r < 4; r++) outrow[cw + r] = hv[r];
        }
    }
}

// ---------------- tail: depths 6..12 entirely in LDS, one block per batch, 256 threads ----------------
// A fragments loaded ONCE into registers (96 x f16x8 = 384 VGPR; cap 512 via launch_bounds(256,1)).
// bias/Pp staged once into LDS. Depth loop = pure ds_read+MFMA passes; zero global loads inside.
// Per pass p (CTM=1): reads LDS rows [32p, 32p+33], writes rows [16p, 16p+16) -> disjoint from all
// earlier writes; one barrier per pass between reads and in-place writes, one per depth.
__global__ __launch_bounds__(TTHREADS, 1) void tail_kernel(
    const f16_t* __restrict__ Xin, const f16_t* __restrict__ Wt,
    const float* __restrict__ Pp, const float* __restrict__ biasf,
    const int* __restrict__ N0, float* __restrict__ outbuf, int inCols)
{
    __shared__ alignas(16) char ldsX[2*TREG + (384 + 1920)*4];
    float* ldsBias = (float*)(ldsX + 2*TREG);
    float* ldsPp   = ldsBias + 384;
    const int b = blockIdx.x;
    const int tid = threadIdx.x;
    int Nt = N0[b];
    #pragma unroll
    for (int s = 0; s < 6; s++) Nt = nstep_f(Nt);
    if (Nt <= 1) return;                     // finished during conv phase; already recorded

    const int w    = tid >> 6;               // 0..3
    const int lane = tid & 63;
    const int n16  = lane & 15;
    const int q    = lane >> 4;
    const int arow = w*16 + n16;             // row-group 0 rows; +64 for group 1
    const int cw   = w*16 + q*4;
    float* outrow  = outbuf + b*NHC;

    // persistent A fragments: [row-group][tap][kc][segment] -- all indices static (full unroll)
    f16x8 A[2][4][4][3];
    #pragma unroll
    for (int rg = 0; rg < 2; rg++) {
        #pragma unroll
        for (int k = 0; k < 4; k++) {
            const f16_t* ab = Wt + ((size_t)k*384 + arow + rg*64)*128 + q*8;
            #pragma unroll
            for (int kc = 0; kc < 4; kc++) {
                A[rg][k][kc][0] = *(const f16x8*)(ab + kc*32);
                A[rg][k][kc][1] = *(const f16x8*)(ab + 16384 + kc*32);   // +128 rows
                A[rg][k][kc][2] = *(const f16x8*)(ab + 32768 + kc*32);   // +256 rows
            }
        }
    }

    // stage X6 (up to 256 rows from buffer, rows 256-257 zeroed) into parity-split padded LDS
    const char* XinB = (const char*)(Xin + (size_t)b*inCols*NHC);
    for (int it = 0; it < 17; ++it) {
        int idx = it*TTHREADS + tid;         // 258 rows x 16 chunks = 4128
        if (idx < 258*16) {
            int row = idx >> 4, cb = (idx & 15) * 16;
            float4 v = {0.f,0.f,0.f,0.f};
            if (row < inCols) v = *(const float4*)(XinB + row*256 + cb);
            *(float4*)(ldsX + (row&1)*TREG + (row>>1)*LDSROWPITCH + cb) = v;
        }
    }
    for (int i = tid; i < 384;  i += TTHREADS) ldsBias[i] = biasf[i];
    for (int i = tid; i < 1920; i += TTHREADS) ldsPp[i]   = Pp[i];
    __syncthreads();

    for (int t = 6; t < 13; ++t) {
        int Nt1 = nstep_f(Nt);
        bool newly = (Nt1 == 1);             // Nt > 1 guaranteed inside the loop
        float dval = log1pf((float)t);
        int np = (Nt1 >> 4) + 1; if (np > 8) np = 8;   // passes; covers col Nt1 with zeros
        for (int p = 0; p < np; ++p) {
            f32x4 acc[2][3] = {};            // [row-group][segment]
            #pragma unroll
            for (int k = 0; k < 4; k++) {
                const char* bb0 = ldsX + (k&1)*TREG + ((k>>1) + p*16 + n16)*LDSROWPITCH + q*16;
                #pragma unroll
                for (int kc = 0; kc < 4; kc++) {
                    f16x8 bb = *(const f16x8*)(bb0 + kc*64);
                    #pragma unroll
                    for (int rg = 0; rg < 2; rg++) {
                        acc[rg][0] = __builtin_amdgcn_mfma_f32_16x16x32_f16(A[rg][k][kc][0], bb, acc[rg][0], 0, 0, 0);
                        acc[rg][1] = __builtin_amdgcn_mfma_f32_16x16x32_f16(A[rg][k][kc][1], bb, acc[rg][1], 0, 0, 0);
                        acc[rg][2] = __builtin_amdgcn_mfma_f32_16x16x32_f16(A[rg][k][kc][2], bb, acc[rg][2], 0, 0, 0);
                    }
                }
            }
            __syncthreads();                 // all LDS reads complete before in-place writes

            int j = p*16 + n16;
            int cnt = Nt - 2*j; cnt = cnt < 0 ? 0 : (cnt > 4 ? 4 : cnt);
            bool zero = (j >= Nt1);
            #pragma unroll
            for (int rg = 0; rg < 2; rg++) {
                int cwr = cw + rg*64;
                float hv[4];
                #pragma unroll
                for (int r = 0; r < 4; r++) {
                    int row = cwr + r;
                    float lv = acc[rg][0][r] + ldsBias[row]       + dval*ldsPp[row*5 + cnt];
                    float rp = acc[rg][1][r] + ldsBias[128 + row] + dval*ldsPp[(128 + row)*5 + cnt];
                    float gp = acc[rg][2][r] + ldsBias[256 + row] + dval*ldsPp[(256 + row)*5 + cnt];
                    float e2 = __expf(2.f*rp);
                    float rv = 1.f - 2.f/(e2 + 1.f);          // tanh
                    float gv = 1.f/(1.f + __expf(-gp));       // sigmoid
                    float hh = lv*gv + rv*(1.f - gv);
                    hv[r] = zero ? 0.f : hh;
                }
                f16x4 hb;
                #pragma unroll
                for (int r = 0; r < 4; r++) hb[r] = (f16_t)hv[r];
                *(f16x4*)(ldsX + (j&1)*TREG + (j>>1)*LDSROWPITCH + cwr*2) = hb;
                if (newly && p == 0 && n16 == 0) {
                    #pragma unroll
                    for (int r = 0; r < 4; r++) outrow[cwr + r] = hv[r];
                }
            }
            // no inter-pass barrier needed: pass p+1 reads rows >= 32p+32 > all writes so far
        }
        if (newly) return;                   // result recorded; this batch is done
        Nt = Nt1;
        __syncthreads();                     // writes visible before next depth's reads
    }
}

// ---------------- finalize: stable rank by finish depth, emit fp32 ----------------
__global__ void finalize_kernel(const float* __restrict__ outbuf,
                                const int* __restrict__ N0, float* __restrict__ dout)
{
    __shared__ int fin[16];
    __shared__ int rnk[16];
    int tid = threadIdx.x;
    if (tid < 16) {
        int n = N0[tid]; int f = 12;
        for (int t = 0; t < 13; t++) { n = nstep_f(n); if (n == 1) { f = t; break; } }
        fin[tid] = f;
    }
    __syncthreads();
    if (tid < 16) {
        int r = 0;
        for (int b2 = 0; b2 < 16; b2++)
            if (fin[b2] < fin[tid] || (fin[b2] == fin[tid] && b2 < tid)) r++;
        rnk[tid] = r;
    }
    __syncthreads();
    for (int e = tid; e < NBATCH*NHC; e += 256) {
        int b = e >> 7, c = e & 127;
        dout[rnk[b]*NHC + c] = outbuf[e];
    }
}

extern "C" void kernel_launch(void* const* d_in, const int* in_sizes, int n_in,
                              void* d_out, int out_size, void* d_ws, size_t ws_size,
                              hipStream_t stream)
{
    const float* h    = (const float*)d_in[0];
    const int*   N0   = (const int*)d_in[1];
    const float* W    = (const float*)d_in[2];
    const float* bvec = (const float*)d_in[3];
    float* dout = (float*)d_out;

    int Ls[14], Ms[14];
    Ls[0] = L0LEN;
    for (int t = 0; t < 13; t++) Ls[t+1] = nstep_f(Ls[t]);
    for (int t = 0; t < 14; t++) Ms[t] = ((Ls[t] + 63) / 64) * 64;

    char* ws = (char*)d_ws;
    size_t off = 0;
    auto alloc = [&](size_t bytes){ size_t o = off; off += (bytes + 255) & ~(size_t)255; return o; };
    size_t oXA   = alloc((size_t)NBATCH * Ms[1] * NHC * 2);   // X1, X3, X5
    size_t oXB   = alloc((size_t)NBATCH * Ms[2] * NHC * 2);   // X2, X4, X6
    size_t oWt   = alloc((size_t)4*384*128*2);
    size_t oPp   = alloc((size_t)384*5*4);
    size_t oBias = alloc((size_t)384*4);
    size_t oOut  = alloc((size_t)NBATCH*NHC*4);
    f16_t* XA    = (f16_t*)(ws + oXA);
    f16_t* XB    = (f16_t*)(ws + oXB);
    f16_t* Wt    = (f16_t*)(ws + oWt);
    float* Pp    = (float*)(ws + oPp);
    float* biasf = (float*)(ws + oBias);
    float* outb  = (float*)(ws + oOut);

    hipLaunchKernelGGL(prep_kernel, dim3(384), dim3(128), 0, stream, W, bvec, Wt, Pp, biasf);

    // t=0 reads h directly (fused transpose); afterwards ping-pong XA/XB
    f16_t* cur = XA; f16_t* nxt = XB;
    hipLaunchKernelGGL(conv_kernel, dim3(Ms[1]/JT, NBATCH), dim3(THREADS), 0, stream,
                       h, (const f16_t*)nullptr, XA, Wt, Pp, biasf, N0, outb,
                       0, Ms[0], Ms[1], log1pf(0.f));
    for (int t = 1; t < 6; t++) {
        hipLaunchKernelGGL(conv_kernel, dim3(Ms[t+1]/JT, NBATCH), dim3(THREADS), 0, stream,
                           h, cur, nxt, Wt, Pp, biasf, N0, outb, t, Ms[t], Ms[t+1], log1pf((float)t));
        f16_t* tmp = cur; cur = nxt; nxt = tmp;
    }
    // cur == X6 (written by t=5 with outCols = Ms[6])
    hipLaunchKernelGGL(tail_kernel, dim3(NBATCH), dim3(TTHREADS), 0, stream,
                       cur, Wt, Pp, biasf, N0, outb, Ms[6]);
    hipLaunchKernelGGL(finalize_kernel, dim3(1), dim3(256), 0, stream, outb, N0, dout);
}